// Round 8
// baseline (359.743 us; speedup 1.0000x reference)
//
#include <hip/hip_runtime.h>
#include <hip/hip_bf16.h>
#include <stdint.h>

// Attention: b=4, n=4097, d=128, h=8, dh=16, scale = d**-0.5.
// Interface (R5-verified): fp32 in, fp32 out; ws >= 33.6MB usable.
// R8 = R7 with the cvt_pkrtz return-type fix (__fp16 vec2 -> bit-identical
// _Float16 vec2 via union). exp2-folded softmax (log2e into Q scale), packed
// f16 cvt, key-split x2 for occupancy (partials merged in out_proj).

#define BB 4
#define NN 4097
#define NNP 4112      // NN padded to 16 (tail tile reads poison=finite, masked)
#define DD 128
#define HH 8
#define DH 16
#define BH (BB*HH)    // 32
#define ROWS (BB*NN)  // 16388

typedef _Float16 h4 __attribute__((ext_vector_type(4)));
typedef _Float16 h2 __attribute__((ext_vector_type(2)));
typedef __fp16   fp16v2 __attribute__((ext_vector_type(2)));  // builtin's native return type
typedef float    f4 __attribute__((ext_vector_type(4)));

#if __has_builtin(__builtin_amdgcn_exp2f)
#define EXP2F(x) __builtin_amdgcn_exp2f(x)
#else
#define EXP2F(x) exp2f(x)
#endif

static __device__ __forceinline__ h4 pack4(float a, float b, float c, float d) {
#if __has_builtin(__builtin_amdgcn_cvt_pkrtz)
    union { h4 v; fp16v2 p[2]; } u;
    u.p[0] = __builtin_amdgcn_cvt_pkrtz(a, b);
    u.p[1] = __builtin_amdgcn_cvt_pkrtz(c, d);
    return u.v;
#else
    h4 r; r[0] = (_Float16)a; r[1] = (_Float16)b; r[2] = (_Float16)c; r[3] = (_Float16)d;
    return r;
#endif
}

// ---------------- K1: qkv = x @ W_qkv + b_qkv -> f16 Qh,Kh (row), Vt (transposed) ----
__global__ __launch_bounds__(384) void qkv_proj(
    const float* __restrict__ x,
    const float* __restrict__ Wqkv,
    const float* __restrict__ bqkv,
    _Float16* __restrict__ Qh,    // [BH][NNP][16], scale*log2e folded
    _Float16* __restrict__ Kh,    // [BH][NNP][16]
    _Float16* __restrict__ Vt)    // [BH][16][NNP]
{
    const int t  = threadIdx.x;        // 0..383 (output column)
    const int r0 = blockIdx.x * 8;     // rows r0..r0+7

    const float bias = bqkv[t];
    float acc[8];
    #pragma unroll
    for (int r = 0; r < 8; ++r) acc[r] = bias;

    const float* xp[8];
    #pragma unroll
    for (int r = 0; r < 8; ++r)
        xp[r] = x + (size_t)((r0 + r < ROWS) ? (r0 + r) : (ROWS - 1)) * DD;

    #pragma unroll 2
    for (int k = 0; k < DD; ++k) {
        const float w = Wqkv[k*384 + t];   // coalesced vector load
        #pragma unroll
        for (int r = 0; r < 8; ++r)        // xp[r][k] wave-uniform -> s_load
            acc[r] += xp[r][k] * w;
    }

    const int which = t >> 7;          // 0=q 1=k 2=v
    const int c     = t & 127;
    const int head  = c >> 4;
    const int i     = c & 15;
    // fold scale * log2(e) into Q so softmax uses raw v_exp (exp2)
    const float QSCALE = 0.08838834764831845f * 1.4426950408889634f;

    #pragma unroll
    for (int r = 0; r < 8; ++r) {
        const int row  = r0 + r;
        if (row >= ROWS) break;
        const int bidx = row / NN;
        const int nrow = row - bidx*NN;
        const int bh   = bidx*HH + head;
        if (which == 0) {
            Qh[((size_t)bh*NNP + nrow)*DH + i] = (_Float16)(acc[r] * QSCALE);
        } else if (which == 1) {
            Kh[((size_t)bh*NNP + nrow)*DH + i] = (_Float16)acc[r];
        } else {
            Vt[((size_t)bh*DH + i)*NNP + nrow] = (_Float16)acc[r];
        }
    }
}

// ---------------- K2: MFMA flash attention, key-split x2 -> partial acc + l ------
__global__ __launch_bounds__(256, 8) void attn_mfma(
    const _Float16* __restrict__ Qh,
    const _Float16* __restrict__ Kh,
    const _Float16* __restrict__ Vt,
    float* __restrict__ PACC,     // [2][ROWS][DD] unnormalized out
    float* __restrict__ PL)       // [2][ROWS][HH] row sums
{
    const int qt   = blockIdx.x;       // 0..32
    const int bh   = blockIdx.y;       // 0..31
    const int sp   = blockIdx.z;       // key split 0/1
    const int tid  = threadIdx.x;
    const int wave = tid >> 6;
    const int lane = tid & 63;
    const int quad = lane >> 4;
    const int l16  = lane & 15;

    const int bidx = bh >> 3, head = bh & 7;

    const int qr0 = qt*128 + wave*16 + l16;
    const int qr1 = qr0 + 64;
    const int qc0 = (qr0 < NN) ? qr0 : (NN-1);
    const int qc1 = (qr1 < NN) ? qr1 : (NN-1);

    const _Float16* Qb = Qh + (size_t)bh*NNP*DH;
    const h4 qf0 = *(const h4*)(Qb + (size_t)qc0*DH + quad*4);
    const h4 qf1 = *(const h4*)(Qb + (size_t)qc1*DH + quad*4);

    f4 acc0 = {0.f,0.f,0.f,0.f}, acc1 = {0.f,0.f,0.f,0.f};
    float ls0 = 0.f, ls1 = 0.f;

    // split 0: tiles [0,129); split 1: tiles [129,256) + masked tail tile 256
    const int t0 = sp ? 129 : 0;
    const int t1 = sp ? 256 : 129;

    const _Float16* kp = Kh + ((size_t)bh*NNP + (size_t)t0*16 + l16)*DH + quad*4;
    const _Float16* vp = Vt + ((size_t)bh*DH + l16)*NNP + t0*16 + quad*4;

    h4 ak = *(const h4*)kp;
    h4 av = *(const h4*)vp;

    const f4 zero = {0.f,0.f,0.f,0.f};
    for (int tt = t0; tt < t1; ++tt) {
        kp += 16*DH; vp += 16;
        const h4 nak = *(const h4*)kp;   // prefetch next tile (tile<=256 always valid)
        const h4 nav = *(const h4*)vp;

        f4 d0 = __builtin_amdgcn_mfma_f32_16x16x16f16(ak, qf0, zero, 0, 0, 0);
        f4 d1 = __builtin_amdgcn_mfma_f32_16x16x16f16(ak, qf1, zero, 0, 0, 0);

        float p00 = EXP2F(d0[0]), p01 = EXP2F(d0[1]), p02 = EXP2F(d0[2]), p03 = EXP2F(d0[3]);
        float p10 = EXP2F(d1[0]), p11 = EXP2F(d1[1]), p12 = EXP2F(d1[2]), p13 = EXP2F(d1[3]);

        ls0 += (p00 + p01) + (p02 + p03);
        ls1 += (p10 + p11) + (p12 + p13);

        const h4 pb0 = pack4(p00, p01, p02, p03);
        const h4 pb1 = pack4(p10, p11, p12, p13);

        acc0 = __builtin_amdgcn_mfma_f32_16x16x16f16(av, pb0, acc0, 0, 0, 0);
        acc1 = __builtin_amdgcn_mfma_f32_16x16x16f16(av, pb1, acc1, 0, 0, 0);

        ak = nak; av = nav;
    }

    if (sp) {   // tail tile 256: keys 4096..4111, only key 4096 (quad==0,r==0) valid
        f4 d0 = __builtin_amdgcn_mfma_f32_16x16x16f16(ak, qf0, zero, 0, 0, 0);
        f4 d1 = __builtin_amdgcn_mfma_f32_16x16x16f16(ak, qf1, zero, 0, 0, 0);
        float p00 = (quad == 0) ? EXP2F(d0[0]) : 0.f;
        float p10 = (quad == 0) ? EXP2F(d1[0]) : 0.f;
        ls0 += p00; ls1 += p10;
        const h4 pb0 = pack4(p00, 0.f, 0.f, 0.f);
        const h4 pb1 = pack4(p10, 0.f, 0.f, 0.f);
        acc0 = __builtin_amdgcn_mfma_f32_16x16x16f16(av, pb0, acc0, 0, 0, 0);
        acc1 = __builtin_amdgcn_mfma_f32_16x16x16f16(av, pb1, acc1, 0, 0, 0);
    }

    // replicate per-row l across quads
    ls0 += __shfl_xor(ls0, 16); ls0 += __shfl_xor(ls0, 32);
    ls1 += __shfl_xor(ls1, 16); ls1 += __shfl_xor(ls1, 32);

    const size_t rbase = (size_t)sp * ROWS + (size_t)bidx * NN;
    if (qr0 < NN) {
        *(float4*)(PACC + (rbase + qr0)*DD + head*DH + quad*4)
            = make_float4(acc0[0], acc0[1], acc0[2], acc0[3]);
        if (quad == 0) PL[(rbase + qr0)*HH + head] = ls0;
    }
    if (qr1 < NN) {
        *(float4*)(PACC + (rbase + qr1)*DD + head*DH + quad*4)
            = make_float4(acc1[0], acc1[1], acc1[2], acc1[3]);
        if (quad == 0) PL[(rbase + qr1)*HH + head] = ls1;
    }
}

// ---------------- K3: merge splits + out = AO @ W_out + b_out (fp32) ----------------
__global__ __launch_bounds__(128) void out_proj(
    const float* __restrict__ PACC,
    const float* __restrict__ PL,
    const float* __restrict__ Wout,
    const float* __restrict__ bout,
    float* __restrict__ out)
{
    __shared__ float invl[64];            // [r][h]
    const int t  = threadIdx.x;           // 0..127 (output column)
    const int r0 = blockIdx.x * 8;

    if (t < 64) {
        const int r = t >> 3, h = t & 7;
        const int row = (r0 + r < ROWS) ? (r0 + r) : (ROWS - 1);
        invl[t] = 1.0f / (PL[(size_t)row*HH + h] + PL[((size_t)ROWS + row)*HH + h]);
    }
    __syncthreads();

    float acc[8];
    const float bias = bout[t];
    #pragma unroll
    for (int r = 0; r < 8; ++r) acc[r] = bias;

    const float* A = PACC + (size_t)r0 * DD;            // split-0 rows (uniform -> s_load)
    const float* B = PACC + ((size_t)ROWS + r0) * DD;   // split-1 rows

    #pragma unroll
    for (int h = 0; h < HH; ++h) {
        float pr[8] = {0,0,0,0,0,0,0,0};
        #pragma unroll 4
        for (int kk = 0; kk < 16; ++kk) {
            const int k = h*16 + kk;
            const float w = Wout[k*DD + t];
            #pragma unroll
            for (int r = 0; r < 8; ++r)
                pr[r] += (A[r*DD + k] + B[r*DD + k]) * w;
        }
        #pragma unroll
        for (int r = 0; r < 8; ++r) acc[r] += pr[r] * invl[r*8 + h];
    }

    #pragma unroll
    for (int r = 0; r < 8; ++r) {
        const int row = r0 + r;
        if (row < ROWS) out[(size_t)row*DD + t] = acc[r];
    }
}

extern "C" void kernel_launch(void* const* d_in, const int* in_sizes, int n_in,
                              void* d_out, int out_size, void* d_ws, size_t ws_size,
                              hipStream_t stream) {
    const float* x    = (const float*)d_in[0];
    const float* Wqkv = (const float*)d_in[1];
    const float* bqkv = (const float*)d_in[2];
    const float* Wout = (const float*)d_in[3];
    const float* bout = (const float*)d_in[4];
    for (int i = 0; i < n_in; ++i) {
        switch (in_sizes[i]) {
            case 2097664: x    = (const float*)d_in[i]; break;
            case 49152:   Wqkv = (const float*)d_in[i]; break;
            case 384:     bqkv = (const float*)d_in[i]; break;
            case 16384:   Wout = (const float*)d_in[i]; break;
            case 128:     bout = (const float*)d_in[i]; break;
            default: break;
        }
    }
    float* out = (float*)d_out;

    const size_t perh = (size_t)BH * NNP * DH;          // 2,105,344 f16
    _Float16* Qh  = (_Float16*)d_ws;                    // 4.21 MB
    _Float16* Kh  = Qh + perh;
    _Float16* Vt  = Kh + perh;
    float*    PACC = (float*)(Vt + perh);               // [2][ROWS][DD] 16.8 MB
    float*    PL   = PACC + (size_t)2*ROWS*DD;          // [2][ROWS][HH] 1.05 MB
                                                        // total ~30.5 MB (ws>=33.6 proven)

    hipLaunchKernelGGL(qkv_proj, dim3((ROWS+7)/8), dim3(384), 0, stream,
                       x, Wqkv, bqkv, Qh, Kh, Vt);
    hipLaunchKernelGGL(attn_mfma, dim3(33, BH, 2), dim3(256), 0, stream,
                       Qh, Kh, Vt, PACC, PL);
    hipLaunchKernelGGL(out_proj, dim3((ROWS+7)/8), dim3(128), 0, stream,
                       PACC, PL, Wout, bout, out);
}

// Round 9
// 275.117 us; speedup vs baseline: 1.3076x; 1.3076x over previous
//
#include <hip/hip_runtime.h>
#include <hip/hip_bf16.h>
#include <stdint.h>

// Attention: b=4, n=4097, d=128, h=8, dh=16, scale = d**-0.5.
// Interface (R5): fp32 in, fp32 out, ws >= 33.6MB.
// R9: (1) qkv_proj 32 rows/block -> V-thread owns 64B contiguous Vt strip
// (kills the 2B/NNP-stride scatter that cost ~100us in R6/R8);
// (2) attn: 64 q-rows per wave (4 groups share each K/V frag), key-split x4,
// per-split normalized f16 partials; (3) merge kernel + R5 out_proj.

#define BB 4
#define NN 4097
#define NNP 4112
#define DD 128
#define HH 8
#define DH 16
#define BH (BB*HH)    // 32
#define ROWS (BB*NN)  // 16388

typedef _Float16 h4 __attribute__((ext_vector_type(4)));
typedef _Float16 h8 __attribute__((ext_vector_type(8)));
typedef __fp16   fp16v2 __attribute__((ext_vector_type(2)));
typedef float    f4 __attribute__((ext_vector_type(4)));

#if __has_builtin(__builtin_amdgcn_exp2f)
#define EXP2F(x) __builtin_amdgcn_exp2f(x)
#else
#define EXP2F(x) exp2f(x)
#endif

static __device__ __forceinline__ h4 pack4(float a, float b, float c, float d) {
#if __has_builtin(__builtin_amdgcn_cvt_pkrtz)
    union { h4 v; fp16v2 p[2]; } u;
    u.p[0] = __builtin_amdgcn_cvt_pkrtz(a, b);
    u.p[1] = __builtin_amdgcn_cvt_pkrtz(c, d);
    return u.v;
#else
    h4 r; r[0] = (_Float16)a; r[1] = (_Float16)b; r[2] = (_Float16)c; r[3] = (_Float16)d;
    return r;
#endif
}

// ---------------- K1: qkv projection, 32 rows/block ----------------
__global__ __launch_bounds__(384) void qkv_proj(
    const float* __restrict__ x,
    const float* __restrict__ Wqkv,
    const float* __restrict__ bqkv,
    _Float16* __restrict__ Qh,    // [BH][NNP][16], scale*log2e folded
    _Float16* __restrict__ Kh,    // [BH][NNP][16]
    _Float16* __restrict__ Vt)    // [BH][16][NNP]
{
    const int t     = threadIdx.x;          // 0..383 (output column)
    const int blk   = blockIdx.x;           // 0..515 (129 per batch)
    const int bidx  = blk / 129;
    const int jj    = blk - bidx*129;
    const int nrow0 = jj * 32;
    const float* xb = x + ((size_t)bidx*NN + nrow0)*DD;

    const int which = t >> 7, c = t & 127, head = c >> 4, i = c & 15;
    const int bh    = bidx*HH + head;
    const float QSCALE = 0.08838834764831845f * 1.4426950408889634f; // 128^-.5 * log2e
    const float bias = bqkv[t];

    if (nrow0 + 32 <= NN) {
        float acc[32];
        #pragma unroll
        for (int r = 0; r < 32; ++r) acc[r] = bias;
        for (int k = 0; k < DD; ++k) {
            const float w = Wqkv[k*384 + t];    // coalesced
            #pragma unroll
            for (int r = 0; r < 32; ++r)        // xb uniform -> scalar loads
                acc[r] += xb[r*DD + k] * w;
        }
        if (which == 0) {
            #pragma unroll
            for (int r = 0; r < 32; ++r)
                Qh[((size_t)bh*NNP + nrow0 + r)*DH + i] = (_Float16)(acc[r]*QSCALE);
        } else if (which == 1) {
            #pragma unroll
            for (int r = 0; r < 32; ++r)
                Kh[((size_t)bh*NNP + nrow0 + r)*DH + i] = (_Float16)acc[r];
        } else {
            h8 buf[4];
            #pragma unroll
            for (int r = 0; r < 32; ++r) buf[r>>3][r&7] = (_Float16)acc[r];
            h8* dst = (h8*)(Vt + ((size_t)bh*DH + i)*NNP + nrow0);  // 64B contig strip
            #pragma unroll
            for (int m = 0; m < 4; ++m) dst[m] = buf[m];
        }
    } else {
        // tail block: single row nrow0 == 4096
        float a0 = bias;
        for (int k = 0; k < DD; ++k) a0 += xb[k] * Wqkv[k*384 + t];
        if (which == 0)      Qh[((size_t)bh*NNP + nrow0)*DH + i] = (_Float16)(a0*QSCALE);
        else if (which == 1) Kh[((size_t)bh*NNP + nrow0)*DH + i] = (_Float16)a0;
        else                 Vt[((size_t)bh*DH + i)*NNP + nrow0] = (_Float16)a0;
    }
}

// ---------------- K2: MFMA flash attention, 64q/wave, split x4 ----------------
__global__ __launch_bounds__(256, 8) void attn_mfma(
    const _Float16* __restrict__ Qh,
    const _Float16* __restrict__ Kh,
    const _Float16* __restrict__ Vt,
    _Float16* __restrict__ PACC,   // [4][ROWS][DD] per-split normalized out (f16)
    float* __restrict__ PL)        // [4][ROWS][HH] per-split row sums
{
    const int qt   = blockIdx.x;       // 0..16 (256 q-rows per block)
    const int bh   = blockIdx.y;       // 0..31
    const int sp   = blockIdx.z;       // 0..3
    const int tid  = threadIdx.x;
    const int wave = tid >> 6;
    const int lane = tid & 63;
    const int quad = lane >> 4;
    const int l16  = lane & 15;
    const int bidx = bh >> 3, head = bh & 7;

    const int qbase = qt*256 + wave*64;

    const _Float16* Qb = Qh + (size_t)bh*NNP*DH;
    h4 qf[4];
    #pragma unroll
    for (int g = 0; g < 4; ++g) {
        const int qr = qbase + g*16 + l16;
        const int qc = (qr < NN) ? qr : (NN-1);
        qf[g] = *(const h4*)(Qb + (size_t)qc*DH + quad*4);
    }

    f4 acc[4] = {{0,0,0,0},{0,0,0,0},{0,0,0,0},{0,0,0,0}};
    float ls[4] = {0.f,0.f,0.f,0.f};

    // splits: [0,64) [64,128) [128,192) [192,256) + peeled masked tile 256 on sp==3
    const int t0 = sp*64;
    const int t1 = t0 + 64;

    const _Float16* kp = Kh + ((size_t)bh*NNP + (size_t)t0*16 + l16)*DH + quad*4;
    const _Float16* vp = Vt + ((size_t)bh*DH + l16)*NNP + t0*16 + quad*4;

    h4 ak = *(const h4*)kp;
    h4 av = *(const h4*)vp;
    const f4 zero = {0.f,0.f,0.f,0.f};

    for (int tt = t0; tt < t1; ++tt) {
        kp += 16*DH; vp += 16;
        const h4 nak = *(const h4*)kp;   // prefetch (tile index <= 256, in-bounds)
        const h4 nav = *(const h4*)vp;
        #pragma unroll
        for (int g = 0; g < 4; ++g) {
            f4 d = __builtin_amdgcn_mfma_f32_16x16x16f16(ak, qf[g], zero, 0, 0, 0);
            const float p0 = EXP2F(d[0]), p1 = EXP2F(d[1]), p2 = EXP2F(d[2]), p3 = EXP2F(d[3]);
            ls[g] += (p0 + p1) + (p2 + p3);
            const h4 pb = pack4(p0, p1, p2, p3);
            acc[g] = __builtin_amdgcn_mfma_f32_16x16x16f16(av, pb, acc[g], 0, 0, 0);
        }
        ak = nak; av = nav;
    }

    if (sp == 3) {   // tile 256: keys 4096..4111; only key 4096 (quad==0, reg 0) valid
        #pragma unroll
        for (int g = 0; g < 4; ++g) {
            f4 d = __builtin_amdgcn_mfma_f32_16x16x16f16(ak, qf[g], zero, 0, 0, 0);
            const float p0 = (quad == 0) ? EXP2F(d[0]) : 0.f;
            ls[g] += p0;
            const h4 pb = pack4(p0, 0.f, 0.f, 0.f);
            acc[g] = __builtin_amdgcn_mfma_f32_16x16x16f16(av, pb, acc[g], 0, 0, 0);
        }
    }

    const size_t rb = (size_t)sp*ROWS + (size_t)bidx*NN;
    #pragma unroll
    for (int g = 0; g < 4; ++g) {
        float l = ls[g];
        l += __shfl_xor(l, 16);
        l += __shfl_xor(l, 32);
        const int qr = qbase + g*16 + l16;
        if (qr < NN) {
            const float inv = 1.0f / l;   // per-split normalize: f16-safe O(1) range
            *(h4*)(PACC + (rb + qr)*DD + head*DH + quad*4)
                = pack4(acc[g][0]*inv, acc[g][1]*inv, acc[g][2]*inv, acc[g][3]*inv);
            if (quad == 0) PL[(rb + qr)*HH + head] = l;
        }
    }
}

// ---------------- K2b: merge 4 splits -> AO fp32 ----------------
__global__ __launch_bounds__(256) void merge_splits(
    const _Float16* __restrict__ PACC,
    const float* __restrict__ PL,
    float* __restrict__ AO)
{
    const int gid = blockIdx.x*256 + threadIdx.x;   // one 8-elem segment each
    if (gid >= ROWS*16) return;
    const int row  = gid >> 4;
    const int seg  = gid & 15;
    const int head = seg >> 1;

    float num[8] = {0,0,0,0,0,0,0,0};
    float lsum = 0.f;
    #pragma unroll
    for (int sp = 0; sp < 4; ++sp) {
        const float l = PL[((size_t)sp*ROWS + row)*HH + head];
        lsum += l;
        const h8 a = *(const h8*)(PACC + ((size_t)sp*ROWS + row)*DD + seg*8);
        #pragma unroll
        for (int j = 0; j < 8; ++j) num[j] += l * (float)a[j];
    }
    const float inv = 1.0f / lsum;   // sum_sp l_sp*(acc_sp/l_sp) / sum_sp l_sp = correct softmax
    float4* o = (float4*)(AO + (size_t)row*DD + seg*8);
    o[0] = make_float4(num[0]*inv, num[1]*inv, num[2]*inv, num[3]*inv);
    o[1] = make_float4(num[4]*inv, num[5]*inv, num[6]*inv, num[7]*inv);
}

// ---------------- K3: out = AO @ W_out + b_out (R5-proven) ----------------
__global__ __launch_bounds__(128) void out_proj(
    const float* __restrict__ AO,
    const float* __restrict__ Wout,
    const float* __restrict__ bout,
    float* __restrict__ out)
{
    const int t  = threadIdx.x;       // 0..127
    const int r0 = blockIdx.x * 4;

    const float bias = bout[t];
    float acc0 = bias, acc1 = bias, acc2 = bias, acc3 = bias;

    const float* a0 = AO + (size_t)r0 * DD;
    #pragma unroll 4
    for (int k = 0; k < DD; ++k) {
        const float w = Wout[k*DD + t];
        acc0 += a0[k]        * w;
        acc1 += a0[DD + k]   * w;
        acc2 += a0[2*DD + k] * w;
        acc3 += a0[3*DD + k] * w;
    }

    out[(size_t)r0*DD + t]     = acc0;
    out[(size_t)(r0+1)*DD + t] = acc1;
    out[(size_t)(r0+2)*DD + t] = acc2;
    out[(size_t)(r0+3)*DD + t] = acc3;
}

extern "C" void kernel_launch(void* const* d_in, const int* in_sizes, int n_in,
                              void* d_out, int out_size, void* d_ws, size_t ws_size,
                              hipStream_t stream) {
    const float* x    = (const float*)d_in[0];
    const float* Wqkv = (const float*)d_in[1];
    const float* bqkv = (const float*)d_in[2];
    const float* Wout = (const float*)d_in[3];
    const float* bout = (const float*)d_in[4];
    for (int i = 0; i < n_in; ++i) {
        switch (in_sizes[i]) {
            case 2097664: x    = (const float*)d_in[i]; break;
            case 49152:   Wqkv = (const float*)d_in[i]; break;
            case 384:     bqkv = (const float*)d_in[i]; break;
            case 16384:   Wout = (const float*)d_in[i]; break;
            case 128:     bout = (const float*)d_in[i]; break;
            default: break;
        }
    }
    float* out = (float*)d_out;

    const size_t perh = (size_t)BH * NNP * DH;          // 2,105,344 f16
    _Float16* Qh   = (_Float16*)d_ws;                   // 4.21 MB
    _Float16* Kh   = Qh + perh;                         // 4.21 MB
    _Float16* Vt   = Kh + perh;                         // 4.21 MB
    _Float16* PACC = Vt + perh;                         // [4][ROWS][DD] f16, 16.8 MB
    float*    PL   = (float*)(PACC + (size_t)4*ROWS*DD);// [4][ROWS][HH] f32, 2.1 MB
                                                        // total 31.5 MB <= 33.6 proven
    float*    AO   = (float*)Qh;                        // 8.39 MB, aliases dead Qh+Kh

    hipLaunchKernelGGL(qkv_proj, dim3(BB*129), dim3(384), 0, stream,
                       x, Wqkv, bqkv, Qh, Kh, Vt);
    hipLaunchKernelGGL(attn_mfma, dim3(17, BH, 4), dim3(256), 0, stream,
                       Qh, Kh, Vt, PACC, PL);
    hipLaunchKernelGGL(merge_splits, dim3((ROWS*16 + 255)/256), dim3(256), 0, stream,
                       PACC, PL, AO);
    hipLaunchKernelGGL(out_proj, dim3(ROWS/4), dim3(128), 0, stream,
                       AO, Wout, bout, out);
}

// Round 10
// 221.699 us; speedup vs baseline: 1.6227x; 1.2409x over previous
//
#include <hip/hip_runtime.h>
#include <hip/hip_bf16.h>
#include <stdint.h>

// Attention: b=4, n=4097, d=128, h=8, dh=16, scale = d**-0.5.
// Interface (R5): fp32 in, fp32 out, ws >= 33.6MB usable.
// R10: qkv_proj reverted to R5's proven 4-row structure (R9's 32-row variant
// spilled: VGPR=28 < acc[32], VALUBusy 9.7%, 110us). V goes out row-major
// (Vh), then a dedicated LDS-tiled transpose builds Vt with 256B contiguous
// stores. attn_mfma / merge / out_proj unchanged from R9 (attn <= 104us).

#define BB 4
#define NN 4097
#define NNP 4112
#define DD 128
#define HH 8
#define DH 16
#define BH (BB*HH)    // 32
#define ROWS (BB*NN)  // 16388

typedef _Float16 h4 __attribute__((ext_vector_type(4)));
typedef _Float16 h8 __attribute__((ext_vector_type(8)));
typedef __fp16   fp16v2 __attribute__((ext_vector_type(2)));
typedef float    f4 __attribute__((ext_vector_type(4)));

#if __has_builtin(__builtin_amdgcn_exp2f)
#define EXP2F(x) __builtin_amdgcn_exp2f(x)
#else
#define EXP2F(x) exp2f(x)
#endif

static __device__ __forceinline__ h4 pack4(float a, float b, float c, float d) {
#if __has_builtin(__builtin_amdgcn_cvt_pkrtz)
    union { h4 v; fp16v2 p[2]; } u;
    u.p[0] = __builtin_amdgcn_cvt_pkrtz(a, b);
    u.p[1] = __builtin_amdgcn_cvt_pkrtz(c, d);
    return u.v;
#else
    h4 r; r[0] = (_Float16)a; r[1] = (_Float16)b; r[2] = (_Float16)c; r[3] = (_Float16)d;
    return r;
#endif
}

// ---------------- K1: qkv projection, 4 rows/block (R5-proven register budget) ----
__global__ __launch_bounds__(384) void qkv_proj(
    const float* __restrict__ x,
    const float* __restrict__ Wqkv,
    const float* __restrict__ bqkv,
    _Float16* __restrict__ Qh,    // [BH][NNP][16], scale*log2e folded
    _Float16* __restrict__ Kh,    // [BH][NNP][16]
    _Float16* __restrict__ Vh)    // [BH][NNP][16] row-major (transposed later)
{
    const int t  = threadIdx.x;        // 0..383 (output column)
    const int r0 = blockIdx.x * 4;     // rows r0..r0+3 (ROWS/4 = 4097 blocks)

    const float bias = bqkv[t];
    float acc0 = bias, acc1 = bias, acc2 = bias, acc3 = bias;

    const float* x0 = x + (size_t)r0 * DD;
    #pragma unroll 4
    for (int k = 0; k < DD; ++k) {
        const float w = Wqkv[k*384 + t];   // coalesced vector load
        acc0 += x0[k]        * w;          // x0[*] wave-uniform -> s_load
        acc1 += x0[DD + k]   * w;
        acc2 += x0[2*DD + k] * w;
        acc3 += x0[3*DD + k] * w;
    }

    const int which = t >> 7, c = t & 127, head = c >> 4, i = c & 15;
    const float QSCALE = 0.08838834764831845f * 1.4426950408889634f; // 128^-.5 * log2e
    _Float16* base = (which == 0) ? Qh : ((which == 1) ? Kh : Vh);
    const float mul = (which == 0) ? QSCALE : 1.0f;

    float accs[4] = {acc0, acc1, acc2, acc3};
    #pragma unroll
    for (int r = 0; r < 4; ++r) {
        const int row  = r0 + r;
        const int bidx = row / NN;
        const int nrow = row - bidx*NN;
        base[(((size_t)(bidx*HH + head))*NNP + nrow)*DH + i] = (_Float16)(accs[r] * mul);
    }
}

// ---------------- K1b: Vh [bh][n][16] -> Vt [bh][16][NNP] ----------------
__global__ __launch_bounds__(256) void vt_transpose(
    const _Float16* __restrict__ Vh,
    _Float16* __restrict__ Vt)
{
    __shared__ _Float16 tile[128][DH + 2];   // +2 f16 pad vs bank stride
    const int tl  = blockIdx.x;              // 0..32 (33 tiles of 128 n; tail=16)
    const int bh  = blockIdx.y;              // 0..31
    const int tid = threadIdx.x;             // 0..255
    const int n0  = tl * 128;
    const int rem = (n0 + 128 <= NNP) ? 128 : (NNP - n0);   // 128 or 16

    // load: thread -> (r = tid>>1, half-row of 8 f16); coalesced 16B
    {
        const int r  = tid >> 1;
        const int i8 = (tid & 1) * 8;
        const int rc = (r < rem) ? r : (rem - 1);
        const h8 v = *(const h8*)(Vh + ((size_t)bh*NNP + n0 + rc)*DH + i8);
        #pragma unroll
        for (int j = 0; j < 8; ++j) tile[r][i8 + j] = v[j];
    }
    __syncthreads();

    // store: thread -> (i = tid>>4, nseg = tid&15): 8 f16 contiguous in n
    {
        const int i    = tid >> 4;      // 0..15
        const int nseg = tid & 15;      // 0..15
        if (nseg * 8 < rem) {
            h8 v;
            #pragma unroll
            for (int j = 0; j < 8; ++j) v[j] = tile[nseg*8 + j][i];
            *(h8*)(Vt + ((size_t)bh*DH + i)*NNP + n0 + nseg*8) = v;
        }
    }
}

// ---------------- K2: MFMA flash attention, 64q/wave, split x4 (R9-proven) -------
__global__ __launch_bounds__(256, 8) void attn_mfma(
    const _Float16* __restrict__ Qh,
    const _Float16* __restrict__ Kh,
    const _Float16* __restrict__ Vt,
    _Float16* __restrict__ PACC,   // [4][ROWS][DD] per-split normalized out (f16)
    float* __restrict__ PL)        // [4][ROWS][HH] per-split row sums
{
    const int qt   = blockIdx.x;       // 0..16
    const int bh   = blockIdx.y;       // 0..31
    const int sp   = blockIdx.z;       // 0..3
    const int tid  = threadIdx.x;
    const int wave = tid >> 6;
    const int lane = tid & 63;
    const int quad = lane >> 4;
    const int l16  = lane & 15;
    const int bidx = bh >> 3, head = bh & 7;

    const int qbase = qt*256 + wave*64;

    const _Float16* Qb = Qh + (size_t)bh*NNP*DH;
    h4 qf[4];
    #pragma unroll
    for (int g = 0; g < 4; ++g) {
        const int qr = qbase + g*16 + l16;
        const int qc = (qr < NN) ? qr : (NN-1);
        qf[g] = *(const h4*)(Qb + (size_t)qc*DH + quad*4);
    }

    f4 acc[4] = {{0,0,0,0},{0,0,0,0},{0,0,0,0},{0,0,0,0}};
    float ls[4] = {0.f,0.f,0.f,0.f};

    const int t0 = sp*64;
    const int t1 = t0 + 64;

    const _Float16* kp = Kh + ((size_t)bh*NNP + (size_t)t0*16 + l16)*DH + quad*4;
    const _Float16* vp = Vt + ((size_t)bh*DH + l16)*NNP + t0*16 + quad*4;

    h4 ak = *(const h4*)kp;
    h4 av = *(const h4*)vp;
    const f4 zero = {0.f,0.f,0.f,0.f};

    for (int tt = t0; tt < t1; ++tt) {
        kp += 16*DH; vp += 16;
        const h4 nak = *(const h4*)kp;   // prefetch (tile <= 256 in-bounds)
        const h4 nav = *(const h4*)vp;
        #pragma unroll
        for (int g = 0; g < 4; ++g) {
            f4 d = __builtin_amdgcn_mfma_f32_16x16x16f16(ak, qf[g], zero, 0, 0, 0);
            const float p0 = EXP2F(d[0]), p1 = EXP2F(d[1]), p2 = EXP2F(d[2]), p3 = EXP2F(d[3]);
            ls[g] += (p0 + p1) + (p2 + p3);
            const h4 pb = pack4(p0, p1, p2, p3);
            acc[g] = __builtin_amdgcn_mfma_f32_16x16x16f16(av, pb, acc[g], 0, 0, 0);
        }
        ak = nak; av = nav;
    }

    if (sp == 3) {   // tile 256: keys 4096..4111; only key 4096 (quad==0, reg 0) valid
        #pragma unroll
        for (int g = 0; g < 4; ++g) {
            f4 d = __builtin_amdgcn_mfma_f32_16x16x16f16(ak, qf[g], zero, 0, 0, 0);
            const float p0 = (quad == 0) ? EXP2F(d[0]) : 0.f;
            ls[g] += p0;
            const h4 pb = pack4(p0, 0.f, 0.f, 0.f);
            acc[g] = __builtin_amdgcn_mfma_f32_16x16x16f16(av, pb, acc[g], 0, 0, 0);
        }
    }

    const size_t rb = (size_t)sp*ROWS + (size_t)bidx*NN;
    #pragma unroll
    for (int g = 0; g < 4; ++g) {
        float l = ls[g];
        l += __shfl_xor(l, 16);
        l += __shfl_xor(l, 32);
        const int qr = qbase + g*16 + l16;
        if (qr < NN) {
            const float inv = 1.0f / l;   // per-split normalize: f16-safe range
            *(h4*)(PACC + (rb + qr)*DD + head*DH + quad*4)
                = pack4(acc[g][0]*inv, acc[g][1]*inv, acc[g][2]*inv, acc[g][3]*inv);
            if (quad == 0) PL[(rb + qr)*HH + head] = l;
        }
    }
}

// ---------------- K2b: merge 4 splits -> AO fp32 ----------------
__global__ __launch_bounds__(256) void merge_splits(
    const _Float16* __restrict__ PACC,
    const float* __restrict__ PL,
    float* __restrict__ AO)
{
    const int gid = blockIdx.x*256 + threadIdx.x;
    if (gid >= ROWS*16) return;
    const int row  = gid >> 4;
    const int seg  = gid & 15;
    const int head = seg >> 1;

    float num[8] = {0,0,0,0,0,0,0,0};
    float lsum = 0.f;
    #pragma unroll
    for (int sp = 0; sp < 4; ++sp) {
        const float l = PL[((size_t)sp*ROWS + row)*HH + head];
        lsum += l;
        const h8 a = *(const h8*)(PACC + ((size_t)sp*ROWS + row)*DD + seg*8);
        #pragma unroll
        for (int j = 0; j < 8; ++j) num[j] += l * (float)a[j];
    }
    const float inv = 1.0f / lsum;
    float4* o = (float4*)(AO + (size_t)row*DD + seg*8);
    o[0] = make_float4(num[0]*inv, num[1]*inv, num[2]*inv, num[3]*inv);
    o[1] = make_float4(num[4]*inv, num[5]*inv, num[6]*inv, num[7]*inv);
}

// ---------------- K3: out = AO @ W_out + b_out (R5-proven) ----------------
__global__ __launch_bounds__(128) void out_proj(
    const float* __restrict__ AO,
    const float* __restrict__ Wout,
    const float* __restrict__ bout,
    float* __restrict__ out)
{
    const int t  = threadIdx.x;       // 0..127
    const int r0 = blockIdx.x * 4;

    const float bias = bout[t];
    float acc0 = bias, acc1 = bias, acc2 = bias, acc3 = bias;

    const float* a0 = AO + (size_t)r0 * DD;
    #pragma unroll 4
    for (int k = 0; k < DD; ++k) {
        const float w = Wout[k*DD + t];
        acc0 += a0[k]        * w;
        acc1 += a0[DD + k]   * w;
        acc2 += a0[2*DD + k] * w;
        acc3 += a0[3*DD + k] * w;
    }

    out[(size_t)r0*DD + t]     = acc0;
    out[(size_t)(r0+1)*DD + t] = acc1;
    out[(size_t)(r0+2)*DD + t] = acc2;
    out[(size_t)(r0+3)*DD + t] = acc3;
}

extern "C" void kernel_launch(void* const* d_in, const int* in_sizes, int n_in,
                              void* d_out, int out_size, void* d_ws, size_t ws_size,
                              hipStream_t stream) {
    const float* x    = (const float*)d_in[0];
    const float* Wqkv = (const float*)d_in[1];
    const float* bqkv = (const float*)d_in[2];
    const float* Wout = (const float*)d_in[3];
    const float* bout = (const float*)d_in[4];
    for (int i = 0; i < n_in; ++i) {
        switch (in_sizes[i]) {
            case 2097664: x    = (const float*)d_in[i]; break;
            case 49152:   Wqkv = (const float*)d_in[i]; break;
            case 384:     bqkv = (const float*)d_in[i]; break;
            case 16384:   Wout = (const float*)d_in[i]; break;
            case 128:     bout = (const float*)d_in[i]; break;
            default: break;
        }
    }
    float* out = (float*)d_out;

    const size_t perh = (size_t)BH * NNP * DH;            // 2,105,344 f16
    _Float16* Qh   = (_Float16*)d_ws;                     // 4.21 MB
    _Float16* Kh   = Qh + perh;                           // 4.21 MB
    _Float16* Vt   = Kh + perh;                           // 4.21 MB
    _Float16* Vh   = Vt + perh;                           // 4.21 MB (dead after transpose)
    _Float16* PACC = Vh;                                  // [4][ROWS][DD] f16 16.8 MB, overlays Vh
    float*    PL   = (float*)(PACC + (size_t)4*ROWS*DD);  // 2.1 MB -> total 31.5 MB
    float*    AO   = (float*)Qh;                          // 8.39 MB, aliases dead Qh+Kh

    hipLaunchKernelGGL(qkv_proj, dim3(ROWS/4), dim3(384), 0, stream,
                       x, Wqkv, bqkv, Qh, Kh, Vh);
    hipLaunchKernelGGL(vt_transpose, dim3(33, BH), dim3(256), 0, stream,
                       Vh, Vt);
    hipLaunchKernelGGL(attn_mfma, dim3(17, BH, 4), dim3(256), 0, stream,
                       Qh, Kh, Vt, PACC, PL);
    hipLaunchKernelGGL(merge_splits, dim3((ROWS*16 + 255)/256), dim3(256), 0, stream,
                       PACC, PL, AO);
    hipLaunchKernelGGL(out_proj, dim3(ROWS/4), dim3(128), 0, stream,
                       AO, Wout, bout, out);
}

// Round 11
// 203.813 us; speedup vs baseline: 1.7651x; 1.0878x over previous
//
#include <hip/hip_runtime.h>
#include <hip/hip_bf16.h>
#include <stdint.h>

// Attention: b=4, n=4097, d=128, h=8, dh=16, scale = d**-0.5.
// Interface (R5): fp32 in, fp32 out, ws >= 33.6MB usable.
// R11: merge_splits fused into out_proj (kills AO round-trip + one launch);
// attn uses v_dot2_f32_f16 for row-sums (l consistent with f16 P fragments).
// qkv_proj(4-row) + vt_transpose unchanged (R10-proven).

#define BB 4
#define NN 4097
#define NNP 4112
#define DD 128
#define HH 8
#define DH 16
#define BH (BB*HH)    // 32
#define ROWS (BB*NN)  // 16388

typedef _Float16 h4 __attribute__((ext_vector_type(4)));
typedef _Float16 h8 __attribute__((ext_vector_type(8)));
typedef __fp16   fp16v2 __attribute__((ext_vector_type(2)));
typedef float    f4 __attribute__((ext_vector_type(4)));

#if __has_builtin(__builtin_amdgcn_exp2f)
#define EXP2F(x) __builtin_amdgcn_exp2f(x)
#else
#define EXP2F(x) exp2f(x)
#endif

union H4u { h4 v; fp16v2 p[2]; };

static __device__ __forceinline__ H4u pack4u(float a, float b, float c, float d) {
    H4u u;
#if __has_builtin(__builtin_amdgcn_cvt_pkrtz)
    u.p[0] = __builtin_amdgcn_cvt_pkrtz(a, b);
    u.p[1] = __builtin_amdgcn_cvt_pkrtz(c, d);
#else
    u.v[0] = (_Float16)a; u.v[1] = (_Float16)b; u.v[2] = (_Float16)c; u.v[3] = (_Float16)d;
#endif
    return u;
}

// ---------------- K1: qkv projection, 4 rows/block (R10-proven) ----------------
__global__ __launch_bounds__(384) void qkv_proj(
    const float* __restrict__ x,
    const float* __restrict__ Wqkv,
    const float* __restrict__ bqkv,
    _Float16* __restrict__ Qh,    // [BH][NNP][16], scale*log2e folded
    _Float16* __restrict__ Kh,    // [BH][NNP][16]
    _Float16* __restrict__ Vh)    // [BH][NNP][16] row-major (transposed later)
{
    const int t  = threadIdx.x;        // 0..383 (output column)
    const int r0 = blockIdx.x * 4;     // rows r0..r0+3

    const float bias = bqkv[t];
    float acc0 = bias, acc1 = bias, acc2 = bias, acc3 = bias;

    const float* x0 = x + (size_t)r0 * DD;
    #pragma unroll 4
    for (int k = 0; k < DD; ++k) {
        const float w = Wqkv[k*384 + t];   // coalesced
        acc0 += x0[k]        * w;          // wave-uniform -> s_load
        acc1 += x0[DD + k]   * w;
        acc2 += x0[2*DD + k] * w;
        acc3 += x0[3*DD + k] * w;
    }

    const int which = t >> 7, c = t & 127, head = c >> 4, i = c & 15;
    const float QSCALE = 0.08838834764831845f * 1.4426950408889634f; // 128^-.5 * log2e
    _Float16* base = (which == 0) ? Qh : ((which == 1) ? Kh : Vh);
    const float mul = (which == 0) ? QSCALE : 1.0f;

    float accs[4] = {acc0, acc1, acc2, acc3};
    #pragma unroll
    for (int r = 0; r < 4; ++r) {
        const int row  = r0 + r;
        const int bidx = row / NN;
        const int nrow = row - bidx*NN;
        base[(((size_t)(bidx*HH + head))*NNP + nrow)*DH + i] = (_Float16)(accs[r] * mul);
    }
}

// ---------------- K1b: Vh [bh][n][16] -> Vt [bh][16][NNP] ----------------
__global__ __launch_bounds__(256) void vt_transpose(
    const _Float16* __restrict__ Vh,
    _Float16* __restrict__ Vt)
{
    __shared__ _Float16 tile[128][DH + 2];
    const int tl  = blockIdx.x;              // 0..32
    const int bh  = blockIdx.y;              // 0..31
    const int tid = threadIdx.x;             // 0..255
    const int n0  = tl * 128;
    const int rem = (n0 + 128 <= NNP) ? 128 : (NNP - n0);

    {
        const int r  = tid >> 1;
        const int i8 = (tid & 1) * 8;
        const int rc = (r < rem) ? r : (rem - 1);
        const h8 v = *(const h8*)(Vh + ((size_t)bh*NNP + n0 + rc)*DH + i8);
        #pragma unroll
        for (int j = 0; j < 8; ++j) tile[r][i8 + j] = v[j];
    }
    __syncthreads();
    {
        const int i    = tid >> 4;      // 0..15
        const int nseg = tid & 15;      // 0..15
        if (nseg * 8 < rem) {
            h8 v;
            #pragma unroll
            for (int j = 0; j < 8; ++j) v[j] = tile[nseg*8 + j][i];
            *(h8*)(Vt + ((size_t)bh*DH + i)*NNP + n0 + nseg*8) = v;
        }
    }
}

// ---------------- K2: MFMA flash attention, 64q/wave, split x4 ----------------
__global__ __launch_bounds__(256, 8) void attn_mfma(
    const _Float16* __restrict__ Qh,
    const _Float16* __restrict__ Kh,
    const _Float16* __restrict__ Vt,
    _Float16* __restrict__ PACC,   // [4][ROWS][DD] per-split normalized out (f16)
    float* __restrict__ PL)        // [4][ROWS][HH] per-split row sums
{
    const int qt   = blockIdx.x;       // 0..16
    const int bh   = blockIdx.y;       // 0..31
    const int sp   = blockIdx.z;       // 0..3
    const int tid  = threadIdx.x;
    const int wave = tid >> 6;
    const int lane = tid & 63;
    const int quad = lane >> 4;
    const int l16  = lane & 15;
    const int bidx = bh >> 3, head = bh & 7;

    const int qbase = qt*256 + wave*64;

    const _Float16* Qb = Qh + (size_t)bh*NNP*DH;
    h4 qf[4];
    #pragma unroll
    for (int g = 0; g < 4; ++g) {
        const int qr = qbase + g*16 + l16;
        const int qc = (qr < NN) ? qr : (NN-1);
        qf[g] = *(const h4*)(Qb + (size_t)qc*DH + quad*4);
    }

    f4 acc[4] = {{0,0,0,0},{0,0,0,0},{0,0,0,0},{0,0,0,0}};
    float ls[4] = {0.f,0.f,0.f,0.f};

    const int t0 = sp*64;
    const int t1 = t0 + 64;

    const _Float16* kp = Kh + ((size_t)bh*NNP + (size_t)t0*16 + l16)*DH + quad*4;
    const _Float16* vp = Vt + ((size_t)bh*DH + l16)*NNP + t0*16 + quad*4;

    h4 ak = *(const h4*)kp;
    h4 av = *(const h4*)vp;
    const f4 zero = {0.f,0.f,0.f,0.f};
#if __has_builtin(__builtin_amdgcn_fdot2)
    const fp16v2 one2 = {(__fp16)1.0f, (__fp16)1.0f};
#endif

    for (int tt = t0; tt < t1; ++tt) {
        kp += 16*DH; vp += 16;
        const h4 nak = *(const h4*)kp;   // prefetch (tile <= 256 in-bounds)
        const h4 nav = *(const h4*)vp;
        #pragma unroll
        for (int g = 0; g < 4; ++g) {
            f4 d = __builtin_amdgcn_mfma_f32_16x16x16f16(ak, qf[g], zero, 0, 0, 0);
            const float p0 = EXP2F(d[0]), p1 = EXP2F(d[1]), p2 = EXP2F(d[2]), p3 = EXP2F(d[3]);
            const H4u pb = pack4u(p0, p1, p2, p3);
#if __has_builtin(__builtin_amdgcn_fdot2)
            ls[g] = __builtin_amdgcn_fdot2(pb.p[0], one2,
                     __builtin_amdgcn_fdot2(pb.p[1], one2, ls[g], false), false);
#else
            ls[g] += (p0 + p1) + (p2 + p3);
#endif
            acc[g] = __builtin_amdgcn_mfma_f32_16x16x16f16(av, pb.v, acc[g], 0, 0, 0);
        }
        ak = nak; av = nav;
    }

    if (sp == 3) {   // tile 256: keys 4096..4111; only key 4096 (quad==0, reg 0) valid
        #pragma unroll
        for (int g = 0; g < 4; ++g) {
            f4 d = __builtin_amdgcn_mfma_f32_16x16x16f16(ak, qf[g], zero, 0, 0, 0);
            const float p0 = (quad == 0) ? EXP2F(d[0]) : 0.f;
            ls[g] += p0;
            const H4u pb = pack4u(p0, 0.f, 0.f, 0.f);
            acc[g] = __builtin_amdgcn_mfma_f32_16x16x16f16(av, pb.v, acc[g], 0, 0, 0);
        }
    }

    const size_t rb = (size_t)sp*ROWS + (size_t)bidx*NN;
    #pragma unroll
    for (int g = 0; g < 4; ++g) {
        float l = ls[g];
        l += __shfl_xor(l, 16);
        l += __shfl_xor(l, 32);
        const int qr = qbase + g*16 + l16;
        if (qr < NN) {
            const float inv = 1.0f / l;   // per-split normalize: f16-safe range
            const H4u st = pack4u(acc[g][0]*inv, acc[g][1]*inv, acc[g][2]*inv, acc[g][3]*inv);
            *(h4*)(PACC + (rb + qr)*DD + head*DH + quad*4) = st.v;
            if (quad == 0) PL[(rb + qr)*HH + head] = l;
        }
    }
}

// ---------------- K3: fused merge + out = AO @ W_out + b_out ----------------
__global__ __launch_bounds__(128) void out_proj_fused(
    const _Float16* __restrict__ PACC,
    const float* __restrict__ PL,
    const float* __restrict__ Wout,
    const float* __restrict__ bout,
    float* __restrict__ out)
{
    __shared__ float lls[256];     // [sp][r][h]
    __shared__ float linv[64];     // [r][h]
    __shared__ float xr[8*DD];     // merged+normalized AO rows

    const int t  = threadIdx.x;    // 0..127 (output column)
    const int r0 = blockIdx.x * 8; // rows r0..r0+7

    // stage 1: load 256 per-split row sums, reduce over splits
    #pragma unroll
    for (int u = 0; u < 2; ++u) {
        const int idx = t + u*128;
        const int sp = idx >> 6, r = (idx >> 3) & 7, h = idx & 7;
        const int row = (r0 + r < ROWS) ? (r0 + r) : (ROWS - 1);
        lls[idx] = PL[((size_t)sp*ROWS + row)*HH + h];
    }
    __syncthreads();
    if (t < 64) {
        const float s = lls[t] + lls[64 + t] + lls[128 + t] + lls[192 + t];
        linv[t] = 1.0f / s;
    }
    __syncthreads();

    // stage 2: merge splits for this block's 8 rows into xr (normalized)
    const int head = t >> 4;
    #pragma unroll
    for (int r = 0; r < 8; ++r) {
        const int row = (r0 + r < ROWS) ? (r0 + r) : (ROWS - 1);
        float num = 0.f;
        #pragma unroll
        for (int sp = 0; sp < 4; ++sp)
            num += lls[sp*64 + r*8 + head]
                 * (float)PACC[((size_t)sp*ROWS + row)*DD + t];
        xr[r*DD + t] = num * linv[r*8 + head];
    }
    __syncthreads();

    // stage 3: GEMM from LDS
    const float bias = bout[t];
    float acc[8];
    #pragma unroll
    for (int r = 0; r < 8; ++r) acc[r] = bias;

    #pragma unroll 4
    for (int k = 0; k < DD; ++k) {
        const float w = Wout[k*DD + t];   // coalesced
        #pragma unroll
        for (int r = 0; r < 8; ++r)       // xr[r*DD+k] uniform -> LDS broadcast
            acc[r] += xr[r*DD + k] * w;
    }

    #pragma unroll
    for (int r = 0; r < 8; ++r) {
        const int row = r0 + r;
        if (row < ROWS) out[(size_t)row*DD + t] = acc[r];
    }
}

extern "C" void kernel_launch(void* const* d_in, const int* in_sizes, int n_in,
                              void* d_out, int out_size, void* d_ws, size_t ws_size,
                              hipStream_t stream) {
    const float* x    = (const float*)d_in[0];
    const float* Wqkv = (const float*)d_in[1];
    const float* bqkv = (const float*)d_in[2];
    const float* Wout = (const float*)d_in[3];
    const float* bout = (const float*)d_in[4];
    for (int i = 0; i < n_in; ++i) {
        switch (in_sizes[i]) {
            case 2097664: x    = (const float*)d_in[i]; break;
            case 49152:   Wqkv = (const float*)d_in[i]; break;
            case 384:     bqkv = (const float*)d_in[i]; break;
            case 16384:   Wout = (const float*)d_in[i]; break;
            case 128:     bout = (const float*)d_in[i]; break;
            default: break;
        }
    }
    float* out = (float*)d_out;

    const size_t perh = (size_t)BH * NNP * DH;            // 2,105,344 f16
    _Float16* Qh   = (_Float16*)d_ws;                     // 4.21 MB
    _Float16* Kh   = Qh + perh;                           // 4.21 MB
    _Float16* Vt   = Kh + perh;                           // 4.21 MB
    _Float16* Vh   = Vt + perh;                           // 4.21 MB (dead after transpose)
    _Float16* PACC = Vh;                                  // [4][ROWS][DD] f16, overlays Vh
    float*    PL   = (float*)(PACC + (size_t)4*ROWS*DD);  // [4][ROWS][HH] -> total 31.5 MB

    hipLaunchKernelGGL(qkv_proj, dim3(ROWS/4), dim3(384), 0, stream,
                       x, Wqkv, bqkv, Qh, Kh, Vh);
    hipLaunchKernelGGL(vt_transpose, dim3(33, BH), dim3(256), 0, stream,
                       Vh, Vt);
    hipLaunchKernelGGL(attn_mfma, dim3(17, BH, 4), dim3(256), 0, stream,
                       Qh, Kh, Vt, PACC, PL);
    hipLaunchKernelGGL(out_proj_fused, dim3((ROWS + 7)/8), dim3(128), 0, stream,
                       PACC, PL, Wout, bout, out);
}